// Round 1
// baseline (801.350 us; speedup 1.0000x reference)
//
#include <hip/hip_runtime.h>
#include <cstdint>
#include <math.h>

namespace {

constexpr int S = 2048;   // sequence length (both q and k)
constexpr int D = 128;    // head dim
constexpr int BHn = 32;   // B*H
constexpr int BQ = 32;    // q-rows per block
constexpr int BK = 64;    // k per iteration
constexpr int PST = 72;   // padded k-stride (f16 elems) for p_tile/vts: bank step 4/row, 16B-aligned rows
constexpr float L2E = 1.4426950408889634f;

typedef _Float16 half8 __attribute__((ext_vector_type(8)));
typedef _Float16 half4v __attribute__((ext_vector_type(4)));
typedef float floatx4 __attribute__((ext_vector_type(4)));

// Kernel 1: v [BH][S][D] fp32  ->  vt [BH][D][S] f16 (transposed + converted)
// so the main kernel's B fragments are contiguous-k 16B LDS reads.
__global__ __launch_bounds__(256) void convert_v_kernel(const float* __restrict__ v,
                                                        _Float16* __restrict__ vt) {
  __shared__ __align__(16) _Float16 lt[32 * 40];  // [d][k], k-stride 40 keeps b64 reads aligned
  const int t = threadIdx.x;
  const int k0 = blockIdx.x * 32;
  const int d0 = blockIdx.y * 32;
  const int bh = blockIdx.z;
  {
    const int kr = t >> 3;          // 0..31
    const int c4 = (t & 7) * 4;     // 0..28
    float4 a = *(const float4*)(v + ((size_t)bh * S + k0 + kr) * D + d0 + c4);
    lt[(c4 + 0) * 40 + kr] = (_Float16)a.x;
    lt[(c4 + 1) * 40 + kr] = (_Float16)a.y;
    lt[(c4 + 2) * 40 + kr] = (_Float16)a.z;
    lt[(c4 + 3) * 40 + kr] = (_Float16)a.w;
  }
  __syncthreads();
  {
    const int dl = t >> 3;
    const int c4 = (t & 7) * 4;
    half4v o = *(const half4v*)(lt + dl * 40 + c4);
    *(half4v*)(vt + ((size_t)bh * D + d0 + dl) * S + k0 + c4) = o;
  }
}

// Kernel 2: flash-style online-softmax @ V.
// Block: 256 thr = 4 waves. Each block: 32 q-rows; wave w owns d-cols [32w, 32w+32).
// Per k-iter: scores->regs, per-row max/sum via 8-lane shuffle groups, exp->f16 P in LDS,
// V^T tile staged to LDS, rescale accs by alpha, 8 mfma_f32_16x16x32_f16 per wave.
template <bool ONFLY>
__global__ __launch_bounds__(256) void softmax_v_kernel(const float* __restrict__ scores,
                                                        const float* __restrict__ v,
                                                        const _Float16* __restrict__ vt,
                                                        float* __restrict__ out) {
  __shared__ __align__(16) _Float16 p_tile[BQ * PST];  // [q][k] f16, 4608 B
  __shared__ __align__(16) _Float16 vts[D * PST];      // [d][k] f16, 18432 B
  __shared__ __align__(16) float m_state[BQ];
  __shared__ __align__(16) float l_state[BQ];
  __shared__ __align__(16) float alpha_s[BQ];

  const int t = threadIdx.x;
  const int lane = t & 63;
  const int wave = t >> 6;
  const int bh = blockIdx.x & (BHn - 1);   // bh fastest -> XCD = bh%8 (L2 locality for vt)
  const int q0 = (blockIdx.x >> 5) * BQ;
  const int d0 = wave * 32;

  if (t < BQ) { m_state[t] = -INFINITY; l_state[t] = 0.0f; }

  floatx4 acc[2][2];
#pragma unroll
  for (int a = 0; a < 2; a++)
#pragma unroll
    for (int b = 0; b < 2; b++) acc[a][b] = floatx4{0.0f, 0.0f, 0.0f, 0.0f};

  const int r = t >> 3;        // stats: row 0..31, 8 threads per row
  const int c = (t & 7) * 4;   // cols c and c+32
  const float* srow = scores + ((size_t)bh * S + q0 + r) * S;
  const int g = lane >> 4;     // quad within wave
  const int n = lane & 15;     // MFMA m/n index

  for (int k0 = 0; k0 < S; k0 += BK) {
    __syncthreads();  // B1: prev iter's fragment reads done; LDS reusable

    // ---- global loads (issue early) ----
    uint4 vg[4];
    if (!ONFLY) {
      const _Float16* vtb = vt + ((size_t)bh * D) * S + k0;
#pragma unroll
      for (int j = 0; j < 4; j++) {
        const int d = (t >> 3) + 32 * j;
        vg[j] = *(const uint4*)(vtb + (size_t)d * S + (t & 7) * 8);
      }
    }
    float4 s0 = *(const float4*)(srow + k0 + c);
    float4 s1 = *(const float4*)(srow + k0 + c + 32);

    // ---- per-row online-softmax stats + exp (rows owned by 8-lane groups) ----
    float mx = fmaxf(fmaxf(fmaxf(s0.x, s0.y), fmaxf(s0.z, s0.w)),
                     fmaxf(fmaxf(s1.x, s1.y), fmaxf(s1.z, s1.w)));
#pragma unroll
    for (int mm = 1; mm < 8; mm <<= 1) mx = fmaxf(mx, __shfl_xor(mx, mm, 64));
    const float mo = m_state[r];            // broadcast read (same addr per 8 lanes)
    const float mn = fmaxf(mo, mx);
    const float al = exp2f((mo - mn) * L2E);  // first iter: exp(-inf)=0
    float p0 = exp2f((s0.x - mn) * L2E);
    float p1 = exp2f((s0.y - mn) * L2E);
    float p2 = exp2f((s0.z - mn) * L2E);
    float p3 = exp2f((s0.w - mn) * L2E);
    float p4 = exp2f((s1.x - mn) * L2E);
    float p5 = exp2f((s1.y - mn) * L2E);
    float p6 = exp2f((s1.z - mn) * L2E);
    float p7 = exp2f((s1.w - mn) * L2E);
    float sm = ((p0 + p1) + (p2 + p3)) + ((p4 + p5) + (p6 + p7));
#pragma unroll
    for (int mm = 1; mm < 8; mm <<= 1) sm += __shfl_xor(sm, mm, 64);
    half4v ph0 = {(_Float16)p0, (_Float16)p1, (_Float16)p2, (_Float16)p3};
    half4v ph1 = {(_Float16)p4, (_Float16)p5, (_Float16)p6, (_Float16)p7};
    *(half4v*)(p_tile + r * PST + c) = ph0;
    *(half4v*)(p_tile + r * PST + c + 32) = ph1;
    if ((t & 7) == 0) {
      m_state[r] = mn;
      alpha_s[r] = al;
      l_state[r] = l_state[r] * al + sm;
    }

    // ---- stage V^T tile (after stats so vt load latency overlaps exp work) ----
    if (ONFLY) {
#pragma unroll
      for (int j = 0; j < 8; j++) {
        const int kr = (t >> 5) + 8 * j;
        const int dc = (t & 31) * 4;
        float4 vv = *(const float4*)(v + ((size_t)bh * S + k0 + kr) * D + dc);
        vts[(dc + 0) * PST + kr] = (_Float16)vv.x;
        vts[(dc + 1) * PST + kr] = (_Float16)vv.y;
        vts[(dc + 2) * PST + kr] = (_Float16)vv.z;
        vts[(dc + 3) * PST + kr] = (_Float16)vv.w;
      }
    } else {
#pragma unroll
      for (int j = 0; j < 4; j++) {
        const int d = (t >> 3) + 32 * j;
        *(uint4*)(vts + d * PST + (t & 7) * 8) = vg[j];
      }
    }

    __syncthreads();  // B2: p_tile, vts, alpha_s visible

    // ---- rescale accumulators: C/D row = g*4 + reg (+16*qi) ----
#pragma unroll
    for (int qi = 0; qi < 2; qi++) {
      floatx4 av = *(const floatx4*)(alpha_s + 16 * qi + g * 4);
#pragma unroll
      for (int di = 0; di < 2; di++)
#pragma unroll
        for (int rr = 0; rr < 4; rr++) acc[qi][di][rr] *= av[rr];
    }

    // ---- MFMA: A[m=n][k=g*8+j], B[k=g*8+j][n] ----
#pragma unroll
    for (int h = 0; h < 2; h++) {
      const int ko = h * 32 + g * 8;
      half8 a0 = *(const half8*)(p_tile + n * PST + ko);
      half8 a1 = *(const half8*)(p_tile + (16 + n) * PST + ko);
      half8 b0 = *(const half8*)(vts + (d0 + n) * PST + ko);
      half8 b1 = *(const half8*)(vts + (d0 + 16 + n) * PST + ko);
      acc[0][0] = __builtin_amdgcn_mfma_f32_16x16x32_f16(a0, b0, acc[0][0], 0, 0, 0);
      acc[0][1] = __builtin_amdgcn_mfma_f32_16x16x32_f16(a0, b1, acc[0][1], 0, 0, 0);
      acc[1][0] = __builtin_amdgcn_mfma_f32_16x16x32_f16(a1, b0, acc[1][0], 0, 0, 0);
      acc[1][1] = __builtin_amdgcn_mfma_f32_16x16x32_f16(a1, b1, acc[1][1], 0, 0, 0);
    }
  }

  // ---- epilogue: O / l, coalesced fp32 stores ----
#pragma unroll
  for (int qi = 0; qi < 2; qi++) {
    floatx4 lv = *(const floatx4*)(l_state + 16 * qi + g * 4);
#pragma unroll
    for (int rr = 0; rr < 4; rr++) {
      const float inv = 1.0f / lv[rr];
      const int row = q0 + 16 * qi + g * 4 + rr;
      float* orow = out + ((size_t)bh * S + row) * D + d0;
      orow[n] = acc[qi][0][rr] * inv;
      orow[16 + n] = acc[qi][1][rr] * inv;
    }
  }
}

}  // namespace

extern "C" void kernel_launch(void* const* d_in, const int* in_sizes, int n_in,
                              void* d_out, int out_size, void* d_ws, size_t ws_size,
                              hipStream_t stream) {
  const float* scores = (const float*)d_in[0];
  const float* v = (const float*)d_in[1];
  float* out = (float*)d_out;
  const size_t vt_bytes = (size_t)BHn * D * S * sizeof(_Float16);  // 16.8 MB
  if (ws_size >= vt_bytes) {
    _Float16* vt = (_Float16*)d_ws;
    convert_v_kernel<<<dim3(S / 32, D / 32, BHn), 256, 0, stream>>>(v, vt);
    softmax_v_kernel<false><<<dim3(BHn * (S / BQ)), 256, 0, stream>>>(scores, v, vt, out);
  } else {
    // workspace too small: convert v on the fly inside the main kernel
    softmax_v_kernel<true><<<dim3(BHn * (S / BQ)), 256, 0, stream>>>(scores, v, nullptr, out);
  }
}

// Round 2
// 781.764 us; speedup vs baseline: 1.0251x; 1.0251x over previous
//
#include <hip/hip_runtime.h>
#include <cstdint>
#include <math.h>

namespace {

constexpr int S = 2048;   // sequence length (both q and k)
constexpr int D = 128;    // head dim
constexpr int BHn = 32;   // B*H
constexpr int BQ = 32;    // q-rows per block
constexpr int BK = 64;    // k per iteration
constexpr int PST = 72;   // padded k-stride (f16 elems): row step 144B -> b128 reads land 2-way max (free)
constexpr float L2E = 1.4426950408889634f;

typedef _Float16 half8 __attribute__((ext_vector_type(8)));
typedef _Float16 half4v __attribute__((ext_vector_type(4)));
typedef float floatx4 __attribute__((ext_vector_type(4)));

#if __has_builtin(__builtin_amdgcn_exp2f)
#define EXP2F(x) __builtin_amdgcn_exp2f(x)
#else
#define EXP2F(x) exp2f(x)
#endif

// Kernel 1: v [BH][S][D] fp32  ->  vt [BH][D][S] f16 (transposed + converted)
// so the main kernel's B fragments are contiguous-k 16B LDS reads.
__global__ __launch_bounds__(256) void convert_v_kernel(const float* __restrict__ v,
                                                        _Float16* __restrict__ vt) {
  __shared__ __align__(16) _Float16 lt[32 * 40];  // [d][k], k-stride 40 keeps b64 reads aligned
  const int t = threadIdx.x;
  const int k0 = blockIdx.x * 32;
  const int d0 = blockIdx.y * 32;
  const int bh = blockIdx.z;
  {
    const int kr = t >> 3;          // 0..31
    const int c4 = (t & 7) * 4;     // 0..28
    float4 a = *(const float4*)(v + ((size_t)bh * S + k0 + kr) * D + d0 + c4);
    lt[(c4 + 0) * 40 + kr] = (_Float16)a.x;
    lt[(c4 + 1) * 40 + kr] = (_Float16)a.y;
    lt[(c4 + 2) * 40 + kr] = (_Float16)a.z;
    lt[(c4 + 3) * 40 + kr] = (_Float16)a.w;
  }
  __syncthreads();
  {
    const int dl = t >> 3;
    const int c4 = (t & 7) * 4;
    half4v o = *(const half4v*)(lt + dl * 40 + c4);
    *(half4v*)(vt + ((size_t)bh * D + d0 + dl) * S + k0 + c4) = o;
  }
}

// Kernel 2: flash-style online-softmax @ V, software-pipelined.
// Block: 256 thr = 4 waves. Each block: 32 q-rows; wave w owns d-cols [32w, 32w+32).
// Pipeline per k-iter: issue next-iter score loads + this-iter vt loads FIRST (register
// dest -> stay in flight across barriers); consume scores prefetched a full iteration ago
// (vmcnt(6), latency hidden); stats via 8-lane shuffle groups with m/l in REGISTERS;
// exp -> f16 P in LDS; vt -> LDS; 8 mfma_f32_16x16x32_f16 per wave.
template <bool ONFLY>
__global__ __launch_bounds__(256) void softmax_v_kernel(const float* __restrict__ scores,
                                                        const float* __restrict__ v,
                                                        const _Float16* __restrict__ vt,
                                                        float* __restrict__ out) {
  __shared__ __align__(16) _Float16 p_tile[BQ * PST];  // [q][k] f16, 4608 B
  __shared__ __align__(16) _Float16 vts[D * PST];      // [d][k] f16, 18432 B
  __shared__ __align__(16) float l_state[BQ];
  __shared__ __align__(16) float alpha_s[BQ];

  const int t = threadIdx.x;
  const int lane = t & 63;
  const int wave = t >> 6;
  const int bh = blockIdx.x & (BHn - 1);   // bh fastest -> XCD = bh%8 (vt L2 locality: 4 heads = 2MB/XCD)
  const int q0 = (blockIdx.x >> 5) * BQ;
  const int d0 = wave * 32;

  floatx4 acc[2][2];
#pragma unroll
  for (int a = 0; a < 2; a++)
#pragma unroll
    for (int b = 0; b < 2; b++) acc[a][b] = floatx4{0.0f, 0.0f, 0.0f, 0.0f};

  const int r = t >> 3;        // stats: row 0..31, 8 threads per row (rows partitioned per wave)
  const int c = (t & 7) * 4;   // cols c and c+32
  const float* srow = scores + ((size_t)bh * S + q0 + r) * S;
  const int g = lane >> 4;     // quad within wave
  const int n = lane & 15;     // MFMA m/n index

  // online-softmax state in registers (identical across each 8-lane row group)
  float m_reg = -INFINITY;
  float l_reg = 0.0f;

  // prologue: prefetch iter-0 scores
  float4 s0c = *(const float4*)(srow + c);
  float4 s1c = *(const float4*)(srow + c + 32);

  for (int k0 = 0; k0 < S; k0 += BK) {
    // ---- issue next-iter score prefetch FIRST (oldest outstanding = cheapest wait) ----
    const int kn = (k0 + BK < S) ? (k0 + BK) : k0;  // branchless; dup-load is L1/L2 hit on last iter
    float4 s0n = *(const float4*)(srow + kn + c);
    float4 s1n = *(const float4*)(srow + kn + c + 32);

    // ---- issue this-iter vt loads (consumed ~300cy later, after stats; L2-resident) ----
    uint4 vg[4];
    if (!ONFLY) {
      const _Float16* vtb = vt + ((size_t)bh * D) * S + k0;
#pragma unroll
      for (int j = 0; j < 4; j++) {
        const int d = (t >> 3) + 32 * j;
        vg[j] = *(const uint4*)(vtb + (size_t)d * S + (t & 7) * 8);
      }
    }

    // ---- stats on s0c/s1c (prefetched last iteration -> vmcnt wait is tiny) ----
    float mx = fmaxf(fmaxf(fmaxf(s0c.x, s0c.y), fmaxf(s0c.z, s0c.w)),
                     fmaxf(fmaxf(s1c.x, s1c.y), fmaxf(s1c.z, s1c.w)));
#pragma unroll
    for (int mm = 1; mm < 8; mm <<= 1) mx = fmaxf(mx, __shfl_xor(mx, mm, 64));
    const float mn = fmaxf(m_reg, mx);
    const float al = EXP2F((m_reg - mn) * L2E);  // first iter: exp2(-inf)=0
    m_reg = mn;
    float p0 = EXP2F((s0c.x - mn) * L2E);
    float p1 = EXP2F((s0c.y - mn) * L2E);
    float p2 = EXP2F((s0c.z - mn) * L2E);
    float p3 = EXP2F((s0c.w - mn) * L2E);
    float p4 = EXP2F((s1c.x - mn) * L2E);
    float p5 = EXP2F((s1c.y - mn) * L2E);
    float p6 = EXP2F((s1c.z - mn) * L2E);
    float p7 = EXP2F((s1c.w - mn) * L2E);
    float sm = ((p0 + p1) + (p2 + p3)) + ((p4 + p5) + (p6 + p7));
#pragma unroll
    for (int mm = 1; mm < 8; mm <<= 1) sm += __shfl_xor(sm, mm, 64);
    l_reg = l_reg * al + sm;
    half4v ph0 = {(_Float16)p0, (_Float16)p1, (_Float16)p2, (_Float16)p3};
    half4v ph1 = {(_Float16)p4, (_Float16)p5, (_Float16)p6, (_Float16)p7};
    *(half4v*)(p_tile + r * PST + c) = ph0;
    *(half4v*)(p_tile + r * PST + c + 32) = ph1;
    if ((t & 7) == 0) alpha_s[r] = al;

    // ---- stage V^T tile ----
    if (ONFLY) {
#pragma unroll
      for (int j = 0; j < 8; j++) {
        const int kr = (t >> 5) + 8 * j;
        const int dc = (t & 31) * 4;
        float4 vv = *(const float4*)(v + ((size_t)bh * S + k0 + kr) * D + dc);
        vts[(dc + 0) * PST + kr] = (_Float16)vv.x;
        vts[(dc + 1) * PST + kr] = (_Float16)vv.y;
        vts[(dc + 2) * PST + kr] = (_Float16)vv.z;
        vts[(dc + 3) * PST + kr] = (_Float16)vv.w;
      }
    } else {
#pragma unroll
      for (int j = 0; j < 4; j++) {
        const int d = (t >> 3) + 32 * j;
        *(uint4*)(vts + d * PST + (t & 7) * 8) = vg[j];
      }
    }

    __syncthreads();  // B2: p_tile, vts, alpha_s visible (score prefetch stays in flight)

    // ---- rescale accumulators: C/D row = g*4 + reg (+16*qi) ----
#pragma unroll
    for (int qi = 0; qi < 2; qi++) {
      floatx4 av = *(const floatx4*)(alpha_s + 16 * qi + g * 4);
#pragma unroll
      for (int di = 0; di < 2; di++)
#pragma unroll
        for (int rr = 0; rr < 4; rr++) acc[qi][di][rr] *= av[rr];
    }

    // ---- MFMA: A[m=n][k=g*8+j], B[k=g*8+j][n] ----
#pragma unroll
    for (int h = 0; h < 2; h++) {
      const int ko = h * 32 + g * 8;
      half8 a0 = *(const half8*)(p_tile + n * PST + ko);
      half8 a1 = *(const half8*)(p_tile + (16 + n) * PST + ko);
      half8 b0 = *(const half8*)(vts + (d0 + n) * PST + ko);
      half8 b1 = *(const half8*)(vts + (d0 + 16 + n) * PST + ko);
      acc[0][0] = __builtin_amdgcn_mfma_f32_16x16x32_f16(a0, b0, acc[0][0], 0, 0, 0);
      acc[0][1] = __builtin_amdgcn_mfma_f32_16x16x32_f16(a0, b1, acc[0][1], 0, 0, 0);
      acc[1][0] = __builtin_amdgcn_mfma_f32_16x16x32_f16(a1, b0, acc[1][0], 0, 0, 0);
      acc[1][1] = __builtin_amdgcn_mfma_f32_16x16x32_f16(a1, b1, acc[1][1], 0, 0, 0);
    }

    __syncthreads();  // B3: fragment reads done; LDS reusable next iteration

    s0c = s0n;
    s1c = s1n;
  }

  // ---- publish l (cross-wave), then epilogue: O / l, coalesced fp32 stores ----
  if ((t & 7) == 0) l_state[r] = l_reg;
  __syncthreads();
#pragma unroll
  for (int qi = 0; qi < 2; qi++) {
    floatx4 lv = *(const floatx4*)(l_state + 16 * qi + g * 4);
#pragma unroll
    for (int rr = 0; rr < 4; rr++) {
      const float inv = 1.0f / lv[rr];
      const int row = q0 + 16 * qi + g * 4 + rr;
      float* orow = out + ((size_t)bh * S + row) * D + d0;
      orow[n] = acc[qi][0][rr] * inv;
      orow[16 + n] = acc[qi][1][rr] * inv;
    }
  }
}

}  // namespace

extern "C" void kernel_launch(void* const* d_in, const int* in_sizes, int n_in,
                              void* d_out, int out_size, void* d_ws, size_t ws_size,
                              hipStream_t stream) {
  const float* scores = (const float*)d_in[0];
  const float* v = (const float*)d_in[1];
  float* out = (float*)d_out;
  const size_t vt_bytes = (size_t)BHn * D * S * sizeof(_Float16);  // 16.8 MB
  if (ws_size >= vt_bytes) {
    _Float16* vt = (_Float16*)d_ws;
    convert_v_kernel<<<dim3(S / 32, D / 32, BHn), 256, 0, stream>>>(v, vt);
    softmax_v_kernel<false><<<dim3(BHn * (S / BQ)), 256, 0, stream>>>(scores, v, vt, out);
  } else {
    // workspace too small: convert v on the fly inside the main kernel
    softmax_v_kernel<true><<<dim3(BHn * (S / BQ)), 256, 0, stream>>>(scores, v, nullptr, out);
  }
}